// Round 17
// baseline (60.971 us; speedup 1.0000x reference)
//
#include <hip/hip_runtime.h>
#include <hip/hip_bf16.h>

// Problem constants
#define NN 4096
#define CC 64
#define C2 32
#define BB 2

// Workspace layout (float offsets)
#define WS_Q1 0
#define WS_K1 8192
#define WS_Q2 16384
#define WS_K2 24576
#define WS_V1 32768
#define WS_V2 163840

typedef __attribute__((ext_vector_type(8))) short bf16x8;
typedef __attribute__((ext_vector_type(4))) float f32x4;

__device__ __forceinline__ unsigned short bf16_rne(float f) {
    union { float f; unsigned u; } x; x.f = f;
    unsigned u = x.u + 0x7fff + ((x.u >> 16) & 1);
    return (unsigned short)(u >> 16);
}
// HIP-API packed f32->bf16 RNE (r12-proven)
__device__ __forceinline__ unsigned pack2(float a, float b) {
    __hip_bfloat162 h = __float22bfloat162_rn(make_float2(a, b));
    unsigned r; __builtin_memcpy(&r, &h, 4); return r;
}
__device__ __forceinline__ float sigm_e2(float x) {   // 1/(1+2^x)
    return __builtin_amdgcn_rcpf(1.0f + __builtin_amdgcn_exp2f(x));
}

// ---------------------------------------------------------------------------
// Stage A: 6 projections (byte-identical to r12-r16).
// ---------------------------------------------------------------------------
__global__ __launch_bounds__(256) void proj_kernel(
    const float* __restrict__ x1, const float* __restrict__ x2,
    const float* __restrict__ wq1, const float* __restrict__ bq1,
    const float* __restrict__ wk1, const float* __restrict__ bk1,
    const float* __restrict__ wv1, const float* __restrict__ bv1,
    const float* __restrict__ wq2, const float* __restrict__ bq2,
    const float* __restrict__ wk2, const float* __restrict__ bk2,
    const float* __restrict__ wv2, const float* __restrict__ bv2,
    float* __restrict__ ws)
{
    const int ln = threadIdx.x & 63;
    const int og = threadIdx.x >> 6;
    const int n  = blockIdx.x * 64 + ln;
    const int p  = blockIdx.y;
    const int b  = blockIdx.z;

    const float* x; const float* w; const float* bias;
    int mode; float* dstf; unsigned short* dstv;
    switch (p) {
      case 0: x = x1; w = wq1; bias = bq1; mode = 0; dstf = ws + WS_Q1; dstv = 0; break;
      case 1: x = x1; w = wk1; bias = bk1; mode = 0; dstf = ws + WS_K1; dstv = 0; break;
      case 2: x = x1; w = wv1; bias = bv1; mode = 2; dstf = 0; dstv = (unsigned short*)(ws + WS_V1); break;
      case 3: x = x2; w = wq2; bias = bq2; mode = 1; dstf = ws + WS_Q2; dstv = 0; break;
      case 4: x = x2; w = wk2; bias = bk2; mode = 1; dstf = ws + WS_K2; dstv = 0; break;
      default:x = x2; w = wv2; bias = bv2; mode = 2; dstf = 0; dstv = (unsigned short*)(ws + WS_V2); break;
    }

    __shared__ float red[4][C2][64];

    float acc[C2];
    #pragma unroll
    for (int o = 0; o < C2; ++o) acc[o] = 0.0f;

    const float* xb = x + ((size_t)b * CC + og * 16) * NN + n;
    #pragma unroll
    for (int ci = 0; ci < 16; ++ci) {
        const float xv = xb[(size_t)ci * NN];
        #pragma unroll
        for (int o = 0; o < C2; ++o)
            acc[o] += w[o * CC + og * 16 + ci] * xv;
    }
    #pragma unroll
    for (int o = 0; o < C2; ++o) red[og][o][ln] = acc[o];
    __syncthreads();

    float f[8];
    #pragma unroll
    for (int j = 0; j < 8; ++j) {
        const int o = og * 8 + j;
        f[j] = red[0][o][ln] + red[1][o][ln] + red[2][o][ln] + red[3][o][ln]
             + bias[o];
    }

    if (mode == 2) {
        #pragma unroll
        for (int j = 0; j < 8; ++j)
            dstv[((size_t)b * C2 + og * 8 + j) * NN + n] = bf16_rne(f[j]);
    } else {
        float r;
        if (mode == 0) {
            r = f[0];
            #pragma unroll
            for (int j = 1; j < 8; ++j) r = fmaxf(r, f[j]);
        } else {
            r = 0.0f;
            #pragma unroll
            for (int j = 0; j < 8; ++j) r += f[j];
        }
        __syncthreads();
        red[og][0][ln] = r;
        __syncthreads();
        if (og == 0) {
            const float a0 = red[0][0][ln], a1 = red[1][0][ln];
            const float a2 = red[2][0][ln], a3 = red[3][0][ln];
            const float rr = (mode == 0)
                ? fmaxf(fmaxf(a0, a1), fmaxf(a2, a3))
                : (a0 + a1 + a2 + a3) * (1.0f / C2);
            dstf[(size_t)b * NN + n] = rr;
        }
    }
}

// ---------------------------------------------------------------------------
// Stage B (register-direct MFMA, NO LDS / NO barriers in main loop):
// B-frag computed in-register (lane l: m = l&15, k = k0+(l>>4)*8+e —
// layout derived from the r14-proven LDS path); A-frag = per-lane 16B
// global read of V[c][k] (4 lanes/row -> 64B segments, L2-resident).
// Block = 512 thr / 8 waves = one 16-m tile; waves split k 8-ways
// (full k per block); single end-of-kernel LDS reduce + fused conv
// epilogue writes d_out. Grid 256 x 4 = 1024 blocks, 8 waves each.
// ---------------------------------------------------------------------------
__global__ __launch_bounds__(512) void attn_mfma(
    const float* __restrict__ q1, const float* __restrict__ k1,
    const float* __restrict__ q2, const float* __restrict__ k2,
    const unsigned short* __restrict__ v1, const unsigned short* __restrict__ v2,
    const float* __restrict__ x1,  const float* __restrict__ x2,
    const float* __restrict__ wc1, const float* __restrict__ bc1,
    const float* __restrict__ wc2, const float* __restrict__ bc2,
    const float* __restrict__ g1,  const float* __restrict__ g2,
    float* __restrict__ out)
{
    __shared__ float red[8][C2 * 16];   // 16 KB: per-wave partial D
    __shared__ float s_s[C2 * 16];      // 2 KB: reduced s[c][m]

    const int tid = threadIdx.x;
    const int wv  = tid >> 6;          // 0..7: k-slice owner
    const int ln  = tid & 63;

    const int z      = blockIdx.y;
    const int branch = z & 1;
    const int b      = z >> 1;
    const int m0     = blockIdx.x * 16;

    const float* q; const float* kv; const unsigned short* vbf; float sl2e;
    if (branch == 0) { q = q1; kv = k2; vbf = v1; sl2e =  1.44269504089f; }
    else             { q = q2; kv = k1; vbf = v2; sl2e = -1.44269504089f; }

    const int m16 = ln & 15;           // m (B n-dim) and V row-within-16
    const int kg  = ln >> 4;           // k subgroup 0..3
    const float qs = q[(size_t)b * NN + m0 + m16] * sl2e;
    const float* kvb = kv + (size_t)b * NN;

    const int wk0 = wv * (NN / 8);     // this wave's 512-k slice
    const unsigned short* vrow0 = vbf + (size_t)(b * C2 + m16) * NN;       // ct=0
    const unsigned short* vrow1 = vbf + (size_t)(b * C2 + 16 + m16) * NN;  // ct=1

    f32x4 acc0 = (f32x4){0.f, 0.f, 0.f, 0.f};
    f32x4 acc1 = (f32x4){0.f, 0.f, 0.f, 0.f};

    #pragma unroll 2
    for (int it = 0; it < (NN / 8) / 32; ++it) {      // 16 iters of K=32
        const int k0 = wk0 + it * 32 + kg * 8;

        const bf16x8 a0 = *(const bf16x8*)(vrow0 + k0);
        const bf16x8 a1 = *(const bf16x8*)(vrow1 + k0);
        const float4 kfa = *(const float4*)(kvb + k0);
        const float4 kfb = *(const float4*)(kvb + k0 + 4);

        const float s0 = sigm_e2(qs * kfa.x), s1 = sigm_e2(qs * kfa.y);
        const float s2 = sigm_e2(qs * kfa.z), s3 = sigm_e2(qs * kfa.w);
        const float s4 = sigm_e2(qs * kfb.x), s5 = sigm_e2(qs * kfb.y);
        const float s6 = sigm_e2(qs * kfb.z), s7 = sigm_e2(qs * kfb.w);

        uint4 wB;
        wB.x = pack2(s0, s1); wB.y = pack2(s2, s3);
        wB.z = pack2(s4, s5); wB.w = pack2(s6, s7);
        bf16x8 bf; __builtin_memcpy(&bf, &wB, 16);

        acc0 = __builtin_amdgcn_mfma_f32_16x16x32_bf16(a0, bf, acc0, 0, 0, 0);
        acc1 = __builtin_amdgcn_mfma_f32_16x16x32_bf16(a1, bf, acc1, 0, 0, 0);
    }

    // ---- dump per-wave partials: D[c][m], c = ct*16 + kg*4 + j, m = m16 ----
    #pragma unroll
    for (int j = 0; j < 4; ++j) {
        red[wv][(kg * 4 + j) * 16 + m16]      = acc0[j];
        red[wv][(16 + kg * 4 + j) * 16 + m16] = acc1[j];
    }
    __syncthreads();

    // ---- reduce 8 waves: thread t covers one (c,m) cell ----
    {
        float s = 0.0f;
        #pragma unroll
        for (int w8 = 0; w8 < 8; ++w8) s += red[w8][tid];
        s_s[tid] = s;
    }
    __syncthreads();

    // ---- fused conv epilogue: thread = (m = tid&15, co = tid>>4, +32) ----
    const float* wmat; const float* bias; const float* x; float gamma;
    float* o;
    if (branch == 0) { wmat = wc2; bias = bc2; x = x1; gamma = g1[0]; o = out; }
    else             { wmat = wc1; bias = bc1; x = x2; gamma = g2[0];
                       o = out + (size_t)BB * CC * NN; }

    const int m   = tid & 15;
    const int co0 = tid >> 4;          // 0..31

    float sv[C2];
    #pragma unroll
    for (int c = 0; c < C2; ++c) sv[c] = s_s[c * 16 + m];

    #pragma unroll
    for (int rep = 0; rep < 2; ++rep) {
        const int co = co0 + rep * 32;
        float a = bias[co];
        #pragma unroll
        for (int c = 0; c < C2; ++c)
            a += wmat[co * C2 + c] * sv[c];
        const size_t idx = ((size_t)b * CC + co) * NN + m0 + m;
        o[idx] = x[idx] + gamma * a;
    }
}

extern "C" void kernel_launch(void* const* d_in, const int* in_sizes, int n_in,
                              void* d_out, int out_size, void* d_ws, size_t ws_size,
                              hipStream_t stream)
{
    const float* x1  = (const float*)d_in[0];
    const float* x2  = (const float*)d_in[1];
    const float* wq1 = (const float*)d_in[2];
    const float* bq1 = (const float*)d_in[3];
    const float* wk1 = (const float*)d_in[4];
    const float* bk1 = (const float*)d_in[5];
    const float* wv1 = (const float*)d_in[6];
    const float* bv1 = (const float*)d_in[7];
    const float* wc1 = (const float*)d_in[8];
    const float* bc1 = (const float*)d_in[9];
    const float* wq2 = (const float*)d_in[10];
    const float* bq2 = (const float*)d_in[11];
    const float* wk2 = (const float*)d_in[12];
    const float* bk2 = (const float*)d_in[13];
    const float* wv2 = (const float*)d_in[14];
    const float* bv2 = (const float*)d_in[15];
    const float* wc2 = (const float*)d_in[16];
    const float* bc2 = (const float*)d_in[17];
    const float* g1  = (const float*)d_in[18];
    const float* g2  = (const float*)d_in[19];

    float* ws  = (float*)d_ws;
    float* out = (float*)d_out;

    proj_kernel<<<dim3(NN / 64, 6, BB), 256, 0, stream>>>(
        x1, x2, wq1, bq1, wk1, bk1, wv1, bv1,
        wq2, bq2, wk2, bk2, wv2, bv2, ws);

    const float* q1 = ws + WS_Q1; const float* k1 = ws + WS_K1;
    const float* q2 = ws + WS_Q2; const float* k2 = ws + WS_K2;
    const unsigned short* v1 = (const unsigned short*)(ws + WS_V1);
    const unsigned short* v2 = (const unsigned short*)(ws + WS_V2);

    attn_mfma<<<dim3(NN / 16, BB * 2), 512, 0, stream>>>(
        q1, k1, q2, k2, v1, v2,
        x1, x2, wc1, bc1, wc2, bc2, g1, g2, out);
}

// Round 18
// 55.079 us; speedup vs baseline: 1.1070x; 1.1070x over previous
//
#include <hip/hip_runtime.h>
#include <hip/hip_bf16.h>

// Problem constants
#define NN 4096
#define CC 64
#define C2 32
#define BB 2

#define NSEG   8          // k-split across blocks
#define M_BLK  16         // m-tile per block (1 wave)
#define KBLK   64         // k per LDS tile
#define KB_ITERS (NN / NSEG / KBLK)   // 8

// Workspace layout (float offsets)
#define WS_Q1 0
#define WS_K1 8192
#define WS_Q2 16384
#define WS_K2 24576
#define WS_V1 32768
#define WS_V2 163840
#define WS_P  294912   // partials: [branch*NSEG+seg][b][c][m]

typedef __attribute__((address_space(1))) const unsigned int GUI;
typedef __attribute__((address_space(3))) unsigned int LUI;
typedef __attribute__((ext_vector_type(8))) short bf16x8;
typedef __attribute__((ext_vector_type(4))) float f32x4;

__device__ __forceinline__ void glds16(const void* g, void* l) {
    __builtin_amdgcn_global_load_lds((GUI*)g, (LUI*)l, 16, 0, 0);
}

__device__ __forceinline__ unsigned short bf16_rne(float f) {
    union { float f; unsigned u; } x; x.f = f;
    unsigned u = x.u + 0x7fff + ((x.u >> 16) & 1);
    return (unsigned short)(u >> 16);
}
// HIP-API packed f32->bf16 RNE (r12-proven)
__device__ __forceinline__ unsigned pack2(float a, float b) {
    __hip_bfloat162 h = __float22bfloat162_rn(make_float2(a, b));
    unsigned r; __builtin_memcpy(&r, &h, 4); return r;
}
__device__ __forceinline__ float sigm_e2(float x) {   // 1/(1+2^x)
    return __builtin_amdgcn_rcpf(1.0f + __builtin_amdgcn_exp2f(x));
}

// ---------------------------------------------------------------------------
// Stage A: 6 projections (byte-identical to r12-r17).
// ---------------------------------------------------------------------------
__global__ __launch_bounds__(256) void proj_kernel(
    const float* __restrict__ x1, const float* __restrict__ x2,
    const float* __restrict__ wq1, const float* __restrict__ bq1,
    const float* __restrict__ wk1, const float* __restrict__ bk1,
    const float* __restrict__ wv1, const float* __restrict__ bv1,
    const float* __restrict__ wq2, const float* __restrict__ bq2,
    const float* __restrict__ wk2, const float* __restrict__ bk2,
    const float* __restrict__ wv2, const float* __restrict__ bv2,
    float* __restrict__ ws)
{
    const int ln = threadIdx.x & 63;
    const int og = threadIdx.x >> 6;
    const int n  = blockIdx.x * 64 + ln;
    const int p  = blockIdx.y;
    const int b  = blockIdx.z;

    const float* x; const float* w; const float* bias;
    int mode; float* dstf; unsigned short* dstv;
    switch (p) {
      case 0: x = x1; w = wq1; bias = bq1; mode = 0; dstf = ws + WS_Q1; dstv = 0; break;
      case 1: x = x1; w = wk1; bias = bk1; mode = 0; dstf = ws + WS_K1; dstv = 0; break;
      case 2: x = x1; w = wv1; bias = bv1; mode = 2; dstf = 0; dstv = (unsigned short*)(ws + WS_V1); break;
      case 3: x = x2; w = wq2; bias = bq2; mode = 1; dstf = ws + WS_Q2; dstv = 0; break;
      case 4: x = x2; w = wk2; bias = bk2; mode = 1; dstf = ws + WS_K2; dstv = 0; break;
      default:x = x2; w = wv2; bias = bv2; mode = 2; dstf = 0; dstv = (unsigned short*)(ws + WS_V2); break;
    }

    __shared__ float red[4][C2][64];

    float acc[C2];
    #pragma unroll
    for (int o = 0; o < C2; ++o) acc[o] = 0.0f;

    const float* xb = x + ((size_t)b * CC + og * 16) * NN + n;
    #pragma unroll
    for (int ci = 0; ci < 16; ++ci) {
        const float xv = xb[(size_t)ci * NN];
        #pragma unroll
        for (int o = 0; o < C2; ++o)
            acc[o] += w[o * CC + og * 16 + ci] * xv;
    }
    #pragma unroll
    for (int o = 0; o < C2; ++o) red[og][o][ln] = acc[o];
    __syncthreads();

    float f[8];
    #pragma unroll
    for (int j = 0; j < 8; ++j) {
        const int o = og * 8 + j;
        f[j] = red[0][o][ln] + red[1][o][ln] + red[2][o][ln] + red[3][o][ln]
             + bias[o];
    }

    if (mode == 2) {
        #pragma unroll
        for (int j = 0; j < 8; ++j)
            dstv[((size_t)b * C2 + og * 8 + j) * NN + n] = bf16_rne(f[j]);
    } else {
        float r;
        if (mode == 0) {
            r = f[0];
            #pragma unroll
            for (int j = 1; j < 8; ++j) r = fmaxf(r, f[j]);
        } else {
            r = 0.0f;
            #pragma unroll
            for (int j = 0; j < 8; ++j) r += f[j];
        }
        __syncthreads();
        red[og][0][ln] = r;
        __syncthreads();
        if (og == 0) {
            const float a0 = red[0][0][ln], a1 = red[1][0][ln];
            const float a2 = red[2][0][ln], a3 = red[3][0][ln];
            const float rr = (mode == 0)
                ? fmaxf(fmaxf(a0, a1), fmaxf(a2, a3))
                : (a0 + a1 + a2 + a3) * (1.0f / C2);
            dstf[(size_t)b * NN + n] = rr;
        }
    }
}

// ---------------------------------------------------------------------------
// Stage B: SINGLE-WAVE blocks (64 thr), no barriers at all. Per 64-k tile:
//   k-loads first (oldest in vmcnt queue) -> 4x glds16 V-tile (r14-proven
//   swizzle: linear dest + XOR'd source) -> 16 sigmoids into 2 in-register
//   B-frags (r17-proven layout: lane l = m(l&15), k=(l>>4)*8+e) overlapping
//   the DMA -> wave-local vmcnt(0) -> 4 swizzled ds_read_b128 + 4 MFMA.
// Both ct MFMAs share one B-frag (no sigmoid duplication). acc = final
// D[c][m] for this k-seg -> partials; reduce+conv kernel finishes.
// Grid 256 x 8 x 4 = 8192 one-wave blocks = 32 waves/CU.
// ---------------------------------------------------------------------------
__global__ __launch_bounds__(64) void attn_mfma(
    const float* __restrict__ q1, const float* __restrict__ k1,
    const float* __restrict__ q2, const float* __restrict__ k2,
    const unsigned short* __restrict__ v1, const unsigned short* __restrict__ v2,
    float* __restrict__ pout)
{
    __shared__ unsigned short vtile[C2 * KBLK];   // 4 KB, rows c stride 128B

    const int l = threadIdx.x;        // 0..63
    const int seg    = blockIdx.y;
    const int z      = blockIdx.z;
    const int branch = z & 1;
    const int b      = z >> 1;
    const int m0     = blockIdx.x * M_BLK;
    const int kstart = seg * (NN / NSEG);

    const float* q; const float* kv; const unsigned short* vbf; float sl2e;
    if (branch == 0) { q = q1; kv = k2; vbf = v1; sl2e =  1.44269504089f; }
    else             { q = q2; kv = k1; vbf = v2; sl2e = -1.44269504089f; }

    const int m16 = l & 15;           // m this lane owns (B n-dim)
    const int kq  = l >> 4;           // k subgroup 0..3
    const float qs = q[(size_t)b * NN + m0 + m16] * sl2e;
    const float* kvb = kv + (size_t)b * NN;

    // V staging: call j covers rows [j*8, j*8+8); lane -> row j*8 + (l>>3),
    // dest slot l&7 (linear), source granule (slot ^ row&7) -- r14 pattern.
    const int vr = l >> 3;            // 0..7 row-within-call
    const int vs = l & 7;             // dest slot
    const unsigned short* vsrc = vbf + ((size_t)b * C2 + vr) * NN
                               + ((vs ^ vr) << 3);

    f32x4 acc0 = (f32x4){0.f, 0.f, 0.f, 0.f};
    f32x4 acc1 = (f32x4){0.f, 0.f, 0.f, 0.f};

    for (int t = 0; t < KB_ITERS; ++t) {
        const int k0 = kstart + t * KBLK;

        // WAR guard: previous tile's ds_reads complete before DMA overwrite
        asm volatile("s_waitcnt lgkmcnt(0)" ::: "memory");

        // k-loads FIRST (oldest): compiler's wait for them leaves DMA in flight
        const float4 ka0 = *(const float4*)(kvb + k0 + kq * 8);
        const float4 kb0 = *(const float4*)(kvb + k0 + kq * 8 + 4);
        const float4 ka1 = *(const float4*)(kvb + k0 + 32 + kq * 8);
        const float4 kb1 = *(const float4*)(kvb + k0 + 32 + kq * 8 + 4);

        // V-tile DMA (4 x 1KB, linear dest)
        #pragma unroll
        for (int j = 0; j < 4; ++j)
            glds16(vsrc + (size_t)j * 8 * NN + k0,
                   (char*)vtile + j * 1024 + l * 16);

        // 16 sigmoids -> 2 B-frags (overlaps DMA)
        uint4 w0, w1;
        w0.x = pack2(sigm_e2(qs * ka0.x), sigm_e2(qs * ka0.y));
        w0.y = pack2(sigm_e2(qs * ka0.z), sigm_e2(qs * ka0.w));
        w0.z = pack2(sigm_e2(qs * kb0.x), sigm_e2(qs * kb0.y));
        w0.w = pack2(sigm_e2(qs * kb0.z), sigm_e2(qs * kb0.w));
        w1.x = pack2(sigm_e2(qs * ka1.x), sigm_e2(qs * ka1.y));
        w1.y = pack2(sigm_e2(qs * ka1.z), sigm_e2(qs * ka1.w));
        w1.z = pack2(sigm_e2(qs * kb1.x), sigm_e2(qs * kb1.y));
        w1.w = pack2(sigm_e2(qs * kb1.z), sigm_e2(qs * kb1.w));
        bf16x8 bf0, bf1;
        __builtin_memcpy(&bf0, &w0, 16);
        __builtin_memcpy(&bf1, &w1, 16);

        asm volatile("s_waitcnt vmcnt(0)" ::: "memory");
        __builtin_amdgcn_sched_barrier(0);

        // 2 K=32 steps x 2 c-tiles; A-frag rows r, granule (kh*4+kq)^(r&7)
        #pragma unroll
        for (int kh = 0; kh < 2; ++kh) {
            const int slot = kh * 4 + kq;
            const int r0 = m16;
            const int r1 = 16 + m16;
            const bf16x8 a0 = *(const bf16x8*)((const char*)vtile
                              + r0 * 128 + ((slot ^ (r0 & 7)) << 4));
            const bf16x8 a1 = *(const bf16x8*)((const char*)vtile
                              + r1 * 128 + ((slot ^ (r1 & 7)) << 4));
            const bf16x8 bfr = kh ? bf1 : bf0;
            acc0 = __builtin_amdgcn_mfma_f32_16x16x32_bf16(a0, bfr, acc0, 0, 0, 0);
            acc1 = __builtin_amdgcn_mfma_f32_16x16x32_bf16(a1, bfr, acc1, 0, 0, 0);
        }
    }

    // write partials: D[c][m], c = kq*4+j (+16 for ct1), m = m0 + m16
    const size_t obase = (((size_t)(branch * NSEG + seg) * BB + b) * C2) * NN;
    #pragma unroll
    for (int j = 0; j < 4; ++j) {
        pout[obase + (size_t)(kq * 4 + j) * NN + m0 + m16]      = acc0[j];
        pout[obase + (size_t)(16 + kq * 4 + j) * NN + m0 + m16] = acc1[j];
    }
}

// ---------------------------------------------------------------------------
// Stage C: fused segment-reduce + output conv + gamma + residual
// (r12-proven form; seg loop unroll 1). Grid (16, 8, 4) = 512 blocks.
// ---------------------------------------------------------------------------
__global__ __launch_bounds__(256) void conv_kernel(
    const float* __restrict__ x1, const float* __restrict__ x2,
    const float* __restrict__ wc1, const float* __restrict__ bc1,
    const float* __restrict__ wc2, const float* __restrict__ bc2,
    const float* __restrict__ g1,  const float* __restrict__ g2,
    const float* __restrict__ p,   float* __restrict__ out)
{
    const int m      = blockIdx.x * 256 + threadIdx.x;
    const int co0    = blockIdx.y * 8;
    const int b      = blockIdx.z >> 1;
    const int branch = blockIdx.z & 1;

    const float* w; const float* bias; const float* x; float gamma; float* o;
    if (branch == 0) { w = wc2; bias = bc2; x = x1; gamma = g1[0]; o = out; }
    else             { w = wc1; bias = bc1; x = x2; gamma = g2[0]; o = out + (size_t)BB * CC * NN; }

    float s[C2];
    #pragma unroll
    for (int c = 0; c < C2; ++c) s[c] = 0.0f;

    #pragma unroll 1
    for (int seg = 0; seg < NSEG; ++seg) {
        const float* sb = p + (((size_t)(branch * NSEG + seg) * BB + b) * C2) * NN + m;
        #pragma unroll
        for (int c = 0; c < C2; ++c)
            s[c] += sb[(size_t)c * NN];
    }

    #pragma unroll
    for (int co = co0; co < co0 + 8; ++co) {
        float a = bias[co];
        #pragma unroll
        for (int c = 0; c < C2; ++c)
            a += w[co * C2 + c] * s[c];
        const size_t idx = ((size_t)b * CC + co) * NN + m;
        o[idx] = x[idx] + gamma * a;
    }
}

extern "C" void kernel_launch(void* const* d_in, const int* in_sizes, int n_in,
                              void* d_out, int out_size, void* d_ws, size_t ws_size,
                              hipStream_t stream)
{
    const float* x1  = (const float*)d_in[0];
    const float* x2  = (const float*)d_in[1];
    const float* wq1 = (const float*)d_in[2];
    const float* bq1 = (const float*)d_in[3];
    const float* wk1 = (const float*)d_in[4];
    const float* bk1 = (const float*)d_in[5];
    const float* wv1 = (const float*)d_in[6];
    const float* bv1 = (const float*)d_in[7];
    const float* wc1 = (const float*)d_in[8];
    const float* bc1 = (const float*)d_in[9];
    const float* wq2 = (const float*)d_in[10];
    const float* bq2 = (const float*)d_in[11];
    const float* wk2 = (const float*)d_in[12];
    const float* bk2 = (const float*)d_in[13];
    const float* wv2 = (const float*)d_in[14];
    const float* bv2 = (const float*)d_in[15];
    const float* wc2 = (const float*)d_in[16];
    const float* bc2 = (const float*)d_in[17];
    const float* g1  = (const float*)d_in[18];
    const float* g2  = (const float*)d_in[19];

    float* ws  = (float*)d_ws;
    float* out = (float*)d_out;

    proj_kernel<<<dim3(NN / 64, 6, BB), 256, 0, stream>>>(
        x1, x2, wq1, bq1, wk1, bk1, wv1, bv1,
        wq2, bq2, wk2, bk2, wv2, bv2, ws);

    const float* q1 = ws + WS_Q1; const float* k1 = ws + WS_K1;
    const float* q2 = ws + WS_Q2; const float* k2 = ws + WS_K2;
    const unsigned short* v1 = (const unsigned short*)(ws + WS_V1);
    const unsigned short* v2 = (const unsigned short*)(ws + WS_V2);
    float* pp = ws + WS_P;

    attn_mfma<<<dim3(NN / M_BLK, NSEG, BB * 2), 64, 0, stream>>>(
        q1, k1, q2, k2, v1, v2, pp);

    conv_kernel<<<dim3(NN / 256, NSEG, BB * 2), 256, 0, stream>>>(
        x1, x2, wc1, bc1, wc2, bc2, g1, g2, pp, out);
}

// Round 20
// 52.504 us; speedup vs baseline: 1.1613x; 1.0490x over previous
//
#include <hip/hip_runtime.h>
#include <hip/hip_bf16.h>

// Problem constants
#define NN 4096
#define CC 64
#define C2 32
#define BB 2

#define NSEG   4          // k-split across blocks (r11: 8 regressed)
#define M_BLK  32         // m-tile per block
#define KBLK   128        // k per LDS tile (halves barrier count vs r14)
#define KB_ITERS (NN / NSEG / KBLK)   // 8

// Workspace layout (float offsets)
#define WS_Q1 0
#define WS_K1 8192
#define WS_Q2 16384
#define WS_K2 24576
#define WS_V1 32768
#define WS_V2 163840
#define WS_P  294912

typedef __attribute__((address_space(1))) const unsigned int GUI;
typedef __attribute__((address_space(3))) unsigned int LUI;
typedef __attribute__((ext_vector_type(8))) short bf16x8;
typedef __attribute__((ext_vector_type(4))) float f32x4;

__device__ __forceinline__ void glds16(const void* g, void* l) {
    __builtin_amdgcn_global_load_lds((GUI*)g, (LUI*)l, 16, 0, 0);
}

__device__ __forceinline__ unsigned short bf16_rne(float f) {
    union { float f; unsigned u; } x; x.f = f;
    unsigned u = x.u + 0x7fff + ((x.u >> 16) & 1);
    return (unsigned short)(u >> 16);
}
// HIP-API packed f32->bf16 RNE (r12-proven)
__device__ __forceinline__ unsigned pack2(float a, float b) {
    __hip_bfloat162 h = __float22bfloat162_rn(make_float2(a, b));
    unsigned r; __builtin_memcpy(&r, &h, 4); return r;
}
__device__ __forceinline__ float sigm_e2(float x) {   // 1/(1+2^x)
    return __builtin_amdgcn_rcpf(1.0f + __builtin_amdgcn_exp2f(x));
}

// slot swizzle: XOR low 3 bits with row&7, preserve bit 3 (16-slot rows)
__device__ __forceinline__ int swz(int slot, int row) {
    return (slot & 8) | ((slot & 7) ^ (row & 7));
}

// ---------------------------------------------------------------------------
// Stage A: 6 projections (byte-identical to r12-r19).
// ---------------------------------------------------------------------------
__global__ __launch_bounds__(256) void proj_kernel(
    const float* __restrict__ x1, const float* __restrict__ x2,
    const float* __restrict__ wq1, const float* __restrict__ bq1,
    const float* __restrict__ wk1, const float* __restrict__ bk1,
    const float* __restrict__ wv1, const float* __restrict__ bv1,
    const float* __restrict__ wq2, const float* __restrict__ bq2,
    const float* __restrict__ wk2, const float* __restrict__ bk2,
    const float* __restrict__ wv2, const float* __restrict__ bv2,
    float* __restrict__ ws)
{
    const int ln = threadIdx.x & 63;
    const int og = threadIdx.x >> 6;
    const int n  = blockIdx.x * 64 + ln;
    const int p  = blockIdx.y;
    const int b  = blockIdx.z;

    const float* x; const float* w; const float* bias;
    int mode; float* dstf; unsigned short* dstv;
    switch (p) {
      case 0: x = x1; w = wq1; bias = bq1; mode = 0; dstf = ws + WS_Q1; dstv = 0; break;
      case 1: x = x1; w = wk1; bias = bk1; mode = 0; dstf = ws + WS_K1; dstv = 0; break;
      case 2: x = x1; w = wv1; bias = bv1; mode = 2; dstf = 0; dstv = (unsigned short*)(ws + WS_V1); break;
      case 3: x = x2; w = wq2; bias = bq2; mode = 1; dstf = ws + WS_Q2; dstv = 0; break;
      case 4: x = x2; w = wk2; bias = bk2; mode = 1; dstf = ws + WS_K2; dstv = 0; break;
      default:x = x2; w = wv2; bias = bv2; mode = 2; dstf = 0; dstv = (unsigned short*)(ws + WS_V2); break;
    }

    __shared__ float red[4][C2][64];

    float acc[C2];
    #pragma unroll
    for (int o = 0; o < C2; ++o) acc[o] = 0.0f;

    const float* xb = x + ((size_t)b * CC + og * 16) * NN + n;
    #pragma unroll
    for (int ci = 0; ci < 16; ++ci) {
        const float xv = xb[(size_t)ci * NN];
        #pragma unroll
        for (int o = 0; o < C2; ++o)
            acc[o] += w[o * CC + og * 16 + ci] * xv;
    }
    #pragma unroll
    for (int o = 0; o < C2; ++o) red[og][o][ln] = acc[o];
    __syncthreads();

    float f[8];
    #pragma unroll
    for (int j = 0; j < 8; ++j) {
        const int o = og * 8 + j;
        f[j] = red[0][o][ln] + red[1][o][ln] + red[2][o][ln] + red[3][o][ln]
             + bias[o];
    }

    if (mode == 2) {
        #pragma unroll
        for (int j = 0; j < 8; ++j)
            dstv[((size_t)b * C2 + og * 8 + j) * NN + n] = bf16_rne(f[j]);
    } else {
        float r;
        if (mode == 0) {
            r = f[0];
            #pragma unroll
            for (int j = 1; j < 8; ++j) r = fmaxf(r, f[j]);
        } else {
            r = 0.0f;
            #pragma unroll
            for (int j = 0; j < 8; ++j) r += f[j];
        }
        __syncthreads();
        red[og][0][ln] = r;
        __syncthreads();
        if (og == 0) {
            const float a0 = red[0][0][ln], a1 = red[1][0][ln];
            const float a2 = red[2][0][ln], a3 = red[3][0][ln];
            const float rr = (mode == 0)
                ? fmaxf(fmaxf(a0, a1), fmaxf(a2, a3))
                : (a0 + a1 + a2 + a3) * (1.0f / C2);
            dstf[(size_t)b * NN + n] = rr;
        }
    }
}

// ---------------------------------------------------------------------------
// Stage B (MFMA, dbuf, 1 barrier/iter, KBLK=128): byte-identical to r19.
// ---------------------------------------------------------------------------
__global__ __launch_bounds__(256) void attn_mfma(
    const float* __restrict__ q1, const float* __restrict__ k1,
    const float* __restrict__ q2, const float* __restrict__ k2,
    const unsigned short* __restrict__ v1, const unsigned short* __restrict__ v2,
    float* __restrict__ pout)
{
    __shared__ unsigned short vtile[2][C2 * KBLK];     // 2 x 8 KB
    __shared__ unsigned short stile[2][M_BLK * KBLK];  // 2 x 8 KB

    const int tid = threadIdx.x;
    const int wv  = tid >> 6;
    const int ln  = tid & 63;

    const int seg    = blockIdx.y;
    const int z      = blockIdx.z;
    const int branch = z & 1;
    const int b      = z >> 1;
    const int m0     = blockIdx.x * M_BLK;
    const int kstart = seg * (NN / NSEG);

    const float* q; const float* kv; const unsigned short* vbf; float sl2e;
    if (branch == 0) { q = q1; kv = k2; vbf = v1; sl2e =  1.44269504089f; }
    else             { q = q2; kv = k1; vbf = v2; sl2e = -1.44269504089f; }

    const int sm = tid & 31;           // S row (m) this thread computes
    const int sc = tid >> 5;           // k-chunk 0..7 (16 k each)
    const float qs = q[(size_t)b * NN + m0 + sm] * sl2e;
    const float* kvb = kv + (size_t)b * NN;

    f32x4 acc[2];
    #pragma unroll
    for (int mt = 0; mt < 2; ++mt) acc[mt] = (f32x4){0.f, 0.f, 0.f, 0.f};

    // V staging: round A rows 0..15, round B rows 16..31; 16 slots/row.
    const int vr = tid >> 4;           // row-within-round 0..15
    const int vs = tid & 15;           // dest slot 0..15
    const unsigned short* vsrcA = vbf + ((size_t)b * C2 + vr) * NN
                                + (size_t)swz(vs, vr) * 8;
    const unsigned short* vsrcB = vsrcA + (size_t)16 * NN;

    auto sigPackWrite = [&](int buf, float4 ka, float4 kb4, float4 kc, float4 kd) {
        float s[16];
        s[0]  = sigm_e2(qs * ka.x);  s[1]  = sigm_e2(qs * ka.y);
        s[2]  = sigm_e2(qs * ka.z);  s[3]  = sigm_e2(qs * ka.w);
        s[4]  = sigm_e2(qs * kb4.x); s[5]  = sigm_e2(qs * kb4.y);
        s[6]  = sigm_e2(qs * kb4.z); s[7]  = sigm_e2(qs * kb4.w);
        s[8]  = sigm_e2(qs * kc.x);  s[9]  = sigm_e2(qs * kc.y);
        s[10] = sigm_e2(qs * kc.z);  s[11] = sigm_e2(qs * kc.w);
        s[12] = sigm_e2(qs * kd.x);  s[13] = sigm_e2(qs * kd.y);
        s[14] = sigm_e2(qs * kd.z);  s[15] = sigm_e2(qs * kd.w);

        uint4 w0, w1;
        w0.x = pack2(s[0],  s[1]);  w0.y = pack2(s[2],  s[3]);
        w0.z = pack2(s[4],  s[5]);  w0.w = pack2(s[6],  s[7]);
        w1.x = pack2(s[8],  s[9]);  w1.y = pack2(s[10], s[11]);
        w1.z = pack2(s[12], s[13]); w1.w = pack2(s[14], s[15]);

        char* srow = (char*)stile[buf] + sm * 256;
        *(uint4*)(srow + (swz(sc * 2,     sm) << 4)) = w0;
        *(uint4*)(srow + (swz(sc * 2 + 1, sm) << 4)) = w1;
    };

    // prologue: stage V[0] + compute S[0]
    glds16(vsrcA + kstart, (char*)vtile[0] + tid * 16);
    glds16(vsrcB + kstart, (char*)vtile[0] + 4096 + tid * 16);
    {
        const float* kvp = kvb + kstart + sc * 16;
        sigPackWrite(0, *(const float4*)(kvp),     *(const float4*)(kvp + 4),
                        *(const float4*)(kvp + 8), *(const float4*)(kvp + 12));
    }
    asm volatile("s_waitcnt vmcnt(0)" ::: "memory");
    __syncthreads();

    const int ct = wv & 1;
    const int ks = wv >> 1;
    const int ac = ct * 16 + (ln & 15);      // V row (c)

    for (int kb = 0; kb < KB_ITERS; ++kb) {
        const int cur = kb & 1;
        const bool more = (kb + 1 < KB_ITERS);

        float4 ka, kb4, kc, kd;
        if (more) {
            const int kn = kstart + (kb + 1) * KBLK;
            glds16(vsrcA + kn, (char*)vtile[cur ^ 1] + tid * 16);
            glds16(vsrcB + kn, (char*)vtile[cur ^ 1] + 4096 + tid * 16);
            const float* kvp = kvb + kn + sc * 16;
            ka  = *(const float4*)(kvp);
            kb4 = *(const float4*)(kvp + 4);
            kc  = *(const float4*)(kvp + 8);
            kd  = *(const float4*)(kvp + 12);
        }

        #pragma unroll
        for (int kh = 0; kh < 2; ++kh) {
            const int slot = ks * 8 + kh * 4 + (ln >> 4);
            const bf16x8 af = *(const bf16x8*)((const char*)vtile[cur]
                              + ac * 256 + (swz(slot, ac) << 4));
            #pragma unroll
            for (int mt = 0; mt < 2; ++mt) {
                const int bm = mt * 16 + (ln & 15);
                const bf16x8 bfr = *(const bf16x8*)((const char*)stile[cur]
                                   + bm * 256 + (swz(slot, bm) << 4));
                acc[mt] = __builtin_amdgcn_mfma_f32_16x16x32_bf16(af, bfr, acc[mt], 0, 0, 0);
            }
        }

        if (more) sigPackWrite(cur ^ 1, ka, kb4, kc, kd);

        asm volatile("s_waitcnt vmcnt(0)" ::: "memory");
        __syncthreads();
    }

    // cross-wave k-half reduction (stile reused as f32 scratch)
    float* red = (float*)stile;
    if (wv >= 2) {
        #pragma unroll
        for (int mt = 0; mt < 2; ++mt)
            *(f32x4*)&red[((wv - 2) * 2 + mt) * 256 + ln * 4] = acc[mt];
    }
    __syncthreads();
    if (wv < 2) {
        const size_t obase = (((size_t)(branch * NSEG + seg) * BB + b) * C2) * NN;
        #pragma unroll
        for (int mt = 0; mt < 2; ++mt) {
            const f32x4 o = *(const f32x4*)&red[(wv * 2 + mt) * 256 + ln * 4];
            acc[mt].x += o.x; acc[mt].y += o.y; acc[mt].z += o.z; acc[mt].w += o.w;
            #pragma unroll
            for (int j = 0; j < 4; ++j) {
                const int c = wv * 16 + (ln >> 4) * 4 + j;
                const int m = m0 + mt * 16 + (ln & 15);
                pout[obase + (size_t)c * NN + m] = acc[mt][j];
            }
        }
    }
}

// ---------------------------------------------------------------------------
// Stage C: fused segment-reduce + conv + gamma + residual (r12-proven).
// Grid y-dim = CC/8 co-groups (r19 bug: was NSEG -- channels 32-63 unwritten).
// ---------------------------------------------------------------------------
__global__ __launch_bounds__(256) void conv_kernel(
    const float* __restrict__ x1, const float* __restrict__ x2,
    const float* __restrict__ wc1, const float* __restrict__ bc1,
    const float* __restrict__ wc2, const float* __restrict__ bc2,
    const float* __restrict__ g1,  const float* __restrict__ g2,
    const float* __restrict__ p,   float* __restrict__ out)
{
    const int m      = blockIdx.x * 256 + threadIdx.x;
    const int co0    = blockIdx.y * 8;
    const int b      = blockIdx.z >> 1;
    const int branch = blockIdx.z & 1;

    const float* w; const float* bias; const float* x; float gamma; float* o;
    if (branch == 0) { w = wc2; bias = bc2; x = x1; gamma = g1[0]; o = out; }
    else             { w = wc1; bias = bc1; x = x2; gamma = g2[0]; o = out + (size_t)BB * CC * NN; }

    float s[C2];
    #pragma unroll
    for (int c = 0; c < C2; ++c) s[c] = 0.0f;

    #pragma unroll 1
    for (int seg = 0; seg < NSEG; ++seg) {
        const float* sb = p + (((size_t)(branch * NSEG + seg) * BB + b) * C2) * NN + m;
        #pragma unroll
        for (int c = 0; c < C2; ++c)
            s[c] += sb[(size_t)c * NN];
    }

    #pragma unroll
    for (int co = co0; co < co0 + 8; ++co) {
        float a = bias[co];
        #pragma unroll
        for (int c = 0; c < C2; ++c)
            a += w[co * C2 + c] * s[c];
        const size_t idx = ((size_t)b * CC + co) * NN + m;
        o[idx] = x[idx] + gamma * a;
    }
}

extern "C" void kernel_launch(void* const* d_in, const int* in_sizes, int n_in,
                              void* d_out, int out_size, void* d_ws, size_t ws_size,
                              hipStream_t stream)
{
    const float* x1  = (const float*)d_in[0];
    const float* x2  = (const float*)d_in[1];
    const float* wq1 = (const float*)d_in[2];
    const float* bq1 = (const float*)d_in[3];
    const float* wk1 = (const float*)d_in[4];
    const float* bk1 = (const float*)d_in[5];
    const float* wv1 = (const float*)d_in[6];
    const float* bv1 = (const float*)d_in[7];
    const float* wc1 = (const float*)d_in[8];
    const float* bc1 = (const float*)d_in[9];
    const float* wq2 = (const float*)d_in[10];
    const float* bq2 = (const float*)d_in[11];
    const float* wk2 = (const float*)d_in[12];
    const float* bk2 = (const float*)d_in[13];
    const float* wv2 = (const float*)d_in[14];
    const float* bv2 = (const float*)d_in[15];
    const float* wc2 = (const float*)d_in[16];
    const float* bc2 = (const float*)d_in[17];
    const float* g1  = (const float*)d_in[18];
    const float* g2  = (const float*)d_in[19];

    float* ws  = (float*)d_ws;
    float* out = (float*)d_out;

    proj_kernel<<<dim3(NN / 64, 6, BB), 256, 0, stream>>>(
        x1, x2, wq1, bq1, wk1, bk1, wv1, bv1,
        wq2, bq2, wk2, bk2, wv2, bv2, ws);

    const float* q1 = ws + WS_Q1; const float* k1 = ws + WS_K1;
    const float* q2 = ws + WS_Q2; const float* k2 = ws + WS_K2;
    const unsigned short* v1 = (const unsigned short*)(ws + WS_V1);
    const unsigned short* v2 = (const unsigned short*)(ws + WS_V2);
    float* pp = ws + WS_P;

    attn_mfma<<<dim3(NN / M_BLK, NSEG, BB * 2), 256, 0, stream>>>(
        q1, k1, q2, k2, v1, v2, pp);

    conv_kernel<<<dim3(NN / 256, CC / 8, BB * 2), 256, 0, stream>>>(
        x1, x2, wc1, bc1, wc2, bc2, g1, g2, pp, out);
}

// Round 21
// 49.886 us; speedup vs baseline: 1.2222x; 1.0525x over previous
//
#include <hip/hip_runtime.h>
#include <hip/hip_bf16.h>

// Problem constants
#define NN 4096
#define CC 64
#define C2 32
#define BB 2

#define NSEG   4          // k-split across blocks (8 regressed r11; 128-KBLK regressed r20)
#define M_BLK  32         // m-tile per block
#define KBLK   64         // k per LDS tile
#define KB_ITERS (NN / NSEG / KBLK)

// Workspace layout (float offsets)
#define WS_Q1 0
#define WS_K1 8192
#define WS_Q2 16384
#define WS_K2 24576
#define WS_V1 32768
#define WS_V2 163840
#define WS_P  294912

typedef __attribute__((address_space(1))) const unsigned int GUI;
typedef __attribute__((address_space(3))) unsigned int LUI;
typedef __attribute__((ext_vector_type(8))) short bf16x8;
typedef __attribute__((ext_vector_type(4))) float f32x4;

__device__ __forceinline__ void glds16(const void* g, void* l) {
    __builtin_amdgcn_global_load_lds((GUI*)g, (LUI*)l, 16, 0, 0);
}

__device__ __forceinline__ unsigned short bf16_rne(float f) {
    union { float f; unsigned u; } x; x.f = f;
    unsigned u = x.u + 0x7fff + ((x.u >> 16) & 1);
    return (unsigned short)(u >> 16);
}
// HIP-API packed f32->bf16 RNE (r12-proven)
__device__ __forceinline__ unsigned pack2(float a, float b) {
    __hip_bfloat162 h = __float22bfloat162_rn(make_float2(a, b));
    unsigned r; __builtin_memcpy(&r, &h, 4); return r;
}
__device__ __forceinline__ float sigm_e2(float x) {   // 1/(1+2^x)
    return __builtin_amdgcn_rcpf(1.0f + __builtin_amdgcn_exp2f(x));
}

// ---------------------------------------------------------------------------
// Stage A: 6 projections (r12-proven form).
// ---------------------------------------------------------------------------
__global__ __launch_bounds__(256) void proj_kernel(
    const float* __restrict__ x1, const float* __restrict__ x2,
    const float* __restrict__ wq1, const float* __restrict__ bq1,
    const float* __restrict__ wk1, const float* __restrict__ bk1,
    const float* __restrict__ wv1, const float* __restrict__ bv1,
    const float* __restrict__ wq2, const float* __restrict__ bq2,
    const float* __restrict__ wk2, const float* __restrict__ bk2,
    const float* __restrict__ wv2, const float* __restrict__ bv2,
    float* __restrict__ ws)
{
    const int ln = threadIdx.x & 63;
    const int og = threadIdx.x >> 6;
    const int n  = blockIdx.x * 64 + ln;
    const int p  = blockIdx.y;
    const int b  = blockIdx.z;

    const float* x; const float* w; const float* bias;
    int mode; float* dstf; unsigned short* dstv;
    switch (p) {
      case 0: x = x1; w = wq1; bias = bq1; mode = 0; dstf = ws + WS_Q1; dstv = 0; break;
      case 1: x = x1; w = wk1; bias = bk1; mode = 0; dstf = ws + WS_K1; dstv = 0; break;
      case 2: x = x1; w = wv1; bias = bv1; mode = 2; dstf = 0; dstv = (unsigned short*)(ws + WS_V1); break;
      case 3: x = x2; w = wq2; bias = bq2; mode = 1; dstf = ws + WS_Q2; dstv = 0; break;
      case 4: x = x2; w = wk2; bias = bk2; mode = 1; dstf = ws + WS_K2; dstv = 0; break;
      default:x = x2; w = wv2; bias = bv2; mode = 2; dstf = 0; dstv = (unsigned short*)(ws + WS_V2); break;
    }

    __shared__ float red[4][C2][64];

    float acc[C2];
    #pragma unroll
    for (int o = 0; o < C2; ++o) acc[o] = 0.0f;

    const float* xb = x + ((size_t)b * CC + og * 16) * NN + n;
    #pragma unroll
    for (int ci = 0; ci < 16; ++ci) {
        const float xv = xb[(size_t)ci * NN];
        #pragma unroll
        for (int o = 0; o < C2; ++o)
            acc[o] += w[o * CC + og * 16 + ci] * xv;
    }
    #pragma unroll
    for (int o = 0; o < C2; ++o) red[og][o][ln] = acc[o];
    __syncthreads();

    float f[8];
    #pragma unroll
    for (int j = 0; j < 8; ++j) {
        const int o = og * 8 + j;
        f[j] = red[0][o][ln] + red[1][o][ln] + red[2][o][ln] + red[3][o][ln]
             + bias[o];
    }

    if (mode == 2) {
        #pragma unroll
        for (int j = 0; j < 8; ++j)
            dstv[((size_t)b * C2 + og * 8 + j) * NN + n] = bf16_rne(f[j]);
    } else {
        float r;
        if (mode == 0) {
            r = f[0];
            #pragma unroll
            for (int j = 1; j < 8; ++j) r = fmaxf(r, f[j]);
        } else {
            r = 0.0f;
            #pragma unroll
            for (int j = 0; j < 8; ++j) r += f[j];
        }
        __syncthreads();
        red[og][0][ln] = r;
        __syncthreads();
        if (og == 0) {
            const float a0 = red[0][0][ln], a1 = red[1][0][ln];
            const float a2 = red[2][0][ln], a3 = red[3][0][ln];
            const float rr = (mode == 0)
                ? fmaxf(fmaxf(a0, a1), fmaxf(a2, a3))
                : (a0 + a1 + a2 + a3) * (1.0f / C2);
            dstf[(size_t)b * NN + n] = rr;
        }
    }
}

// ---------------------------------------------------------------------------
// Stage B (MFMA, dbuf, 1 barrier/iter, M_BLK=32): the measured-best r14
// configuration, byte-identical. 2048 blocks = 8 blocks/CU.
// ---------------------------------------------------------------------------
__global__ __launch_bounds__(256) void attn_mfma(
    const float* __restrict__ q1, const float* __restrict__ k1,
    const float* __restrict__ q2, const float* __restrict__ k2,
    const unsigned short* __restrict__ v1, const unsigned short* __restrict__ v2,
    float* __restrict__ pout)
{
    __shared__ unsigned short vtile[2][C2 * KBLK];     // 2 x 4 KB
    __shared__ unsigned short stile[2][M_BLK * KBLK];  // 2 x 4 KB

    const int tid = threadIdx.x;
    const int wv  = tid >> 6;
    const int ln  = tid & 63;

    const int seg    = blockIdx.y;
    const int z      = blockIdx.z;
    const int branch = z & 1;
    const int b      = z >> 1;
    const int m0     = blockIdx.x * M_BLK;
    const int kstart = seg * (NN / NSEG);

    const float* q; const float* kv; const unsigned short* vbf; float sl2e;
    if (branch == 0) { q = q1; kv = k2; vbf = v1; sl2e =  1.44269504089f; }
    else             { q = q2; kv = k1; vbf = v2; sl2e = -1.44269504089f; }

    const int sm = tid & 31;           // S row (m) this thread computes
    const int sc = tid >> 5;           // k-chunk 0..7 (8 k each)
    const float qs = q[(size_t)b * NN + m0 + sm] * sl2e;
    const float* kvb = kv + (size_t)b * NN;

    f32x4 acc[2];
    #pragma unroll
    for (int mt = 0; mt < 2; ++mt) acc[mt] = (f32x4){0.f, 0.f, 0.f, 0.f};

    const int vc = tid >> 3;           // V c-row 0..31
    const int vs = tid & 7;            // dest slot 0..7
    const unsigned short* vsrc0 = vbf + (size_t)(b * C2 + vc) * NN
                                + ((vs ^ (vc & 7)) << 3);

    // sigmoid + pack + swizzled ds_write of this thread's 8-k chunk
    auto sigPackWrite = [&](int buf, float4 ka, float4 kb4) {
        float s[8];
        s[0] = sigm_e2(qs * ka.x);  s[1] = sigm_e2(qs * ka.y);
        s[2] = sigm_e2(qs * ka.z);  s[3] = sigm_e2(qs * ka.w);
        s[4] = sigm_e2(qs * kb4.x); s[5] = sigm_e2(qs * kb4.y);
        s[6] = sigm_e2(qs * kb4.z); s[7] = sigm_e2(qs * kb4.w);

        uint4 w;
        w.x = pack2(s[0], s[1]); w.y = pack2(s[2], s[3]);
        w.z = pack2(s[4], s[5]); w.w = pack2(s[6], s[7]);

        char* srow = (char*)stile[buf] + sm * 128;
        *(uint4*)(srow + ((sc ^ (sm & 7)) << 4)) = w;
    };

    // prologue: stage V[0] + compute S[0]
    glds16(vsrc0 + kstart, (char*)vtile[0] + tid * 16);
    {
        const float* kvp = kvb + kstart + sc * 8;
        sigPackWrite(0, *(const float4*)(kvp), *(const float4*)(kvp + 4));
    }
    asm volatile("s_waitcnt vmcnt(0)" ::: "memory");
    __syncthreads();

    const int ct  = wv & 1;
    const int ks  = wv >> 1;
    const int col = (ks << 2) + (ln >> 4);   // slot 0..7
    const int ac  = ct * 16 + (ln & 15);     // V row (c)

    for (int kb = 0; kb < KB_ITERS; ++kb) {
        const int cur = kb & 1;
        const bool more = (kb + 1 < KB_ITERS);

        float4 ka, kb4;
        if (more) {
            glds16(vsrc0 + kstart + (kb + 1) * KBLK,
                   (char*)vtile[cur ^ 1] + tid * 16);
            const float* kvp = kvb + kstart + (kb + 1) * KBLK + sc * 8;
            ka  = *(const float4*)(kvp);
            kb4 = *(const float4*)(kvp + 4);
        }

        const bf16x8 af = *(const bf16x8*)((const char*)vtile[cur]
                          + ac * 128 + ((col ^ (ac & 7)) << 4));
        #pragma unroll
        for (int mt = 0; mt < 2; ++mt) {
            const int bm = mt * 16 + (ln & 15);
            const bf16x8 bfr = *(const bf16x8*)((const char*)stile[cur]
                               + bm * 128 + ((col ^ (bm & 7)) << 4));
            acc[mt] = __builtin_amdgcn_mfma_f32_16x16x32_bf16(af, bfr, acc[mt], 0, 0, 0);
        }

        if (more) sigPackWrite(cur ^ 1, ka, kb4);

        asm volatile("s_waitcnt vmcnt(0)" ::: "memory");
        __syncthreads();
    }

    // cross-wave k-half reduction (stile reused as f32 scratch)
    float* red = (float*)stile;
    if (wv >= 2) {
        #pragma unroll
        for (int mt = 0; mt < 2; ++mt)
            *(f32x4*)&red[((wv - 2) * 2 + mt) * 256 + ln * 4] = acc[mt];
    }
    __syncthreads();
    if (wv < 2) {
        const size_t obase = (((size_t)(branch * NSEG + seg) * BB + b) * C2) * NN;
        #pragma unroll
        for (int mt = 0; mt < 2; ++mt) {
            const f32x4 o = *(const f32x4*)&red[(wv * 2 + mt) * 256 + ln * 4];
            acc[mt].x += o.x; acc[mt].y += o.y; acc[mt].z += o.z; acc[mt].w += o.w;
            #pragma unroll
            for (int j = 0; j < 4; ++j) {
                const int c = wv * 16 + (ln >> 4) * 4 + j;
                const int m = m0 + mt * 16 + (ln & 15);
                pout[obase + (size_t)c * NN + m] = acc[mt][j];
            }
        }
    }
}

// ---------------------------------------------------------------------------
// Stage C: fused segment-reduce + output conv + gamma + residual
// (r12-proven; seg loop unroll 1). Grid (16, CC/8, 4) = 512 blocks.
// ---------------------------------------------------------------------------
__global__ __launch_bounds__(256) void conv_kernel(
    const float* __restrict__ x1, const float* __restrict__ x2,
    const float* __restrict__ wc1, const float* __restrict__ bc1,
    const float* __restrict__ wc2, const float* __restrict__ bc2,
    const float* __restrict__ g1,  const float* __restrict__ g2,
    const float* __restrict__ p,   float* __restrict__ out)
{
    const int m      = blockIdx.x * 256 + threadIdx.x;
    const int co0    = blockIdx.y * 8;
    const int b      = blockIdx.z >> 1;
    const int branch = blockIdx.z & 1;

    const float* w; const float* bias; const float* x; float gamma; float* o;
    if (branch == 0) { w = wc2; bias = bc2; x = x1; gamma = g1[0]; o = out; }
    else             { w = wc1; bias = bc1; x = x2; gamma = g2[0]; o = out + (size_t)BB * CC * NN; }

    float s[C2];
    #pragma unroll
    for (int c = 0; c < C2; ++c) s[c] = 0.0f;

    #pragma unroll 1
    for (int seg = 0; seg < NSEG; ++seg) {
        const float* sb = p + (((size_t)(branch * NSEG + seg) * BB + b) * C2) * NN + m;
        #pragma unroll
        for (int c = 0; c < C2; ++c)
            s[c] += sb[(size_t)c * NN];
    }

    #pragma unroll
    for (int co = co0; co < co0 + 8; ++co) {
        float a = bias[co];
        #pragma unroll
        for (int c = 0; c < C2; ++c)
            a += w[co * C2 + c] * s[c];
        const size_t idx = ((size_t)b * CC + co) * NN + m;
        o[idx] = x[idx] + gamma * a;
    }
}

extern "C" void kernel_launch(void* const* d_in, const int* in_sizes, int n_in,
                              void* d_out, int out_size, void* d_ws, size_t ws_size,
                              hipStream_t stream)
{
    const float* x1  = (const float*)d_in[0];
    const float* x2  = (const float*)d_in[1];
    const float* wq1 = (const float*)d_in[2];
    const float* bq1 = (const float*)d_in[3];
    const float* wk1 = (const float*)d_in[4];
    const float* bk1 = (const float*)d_in[5];
    const float* wv1 = (const float*)d_in[6];
    const float* bv1 = (const float*)d_in[7];
    const float* wc1 = (const float*)d_in[8];
    const float* bc1 = (const float*)d_in[9];
    const float* wq2 = (const float*)d_in[10];
    const float* bq2 = (const float*)d_in[11];
    const float* wk2 = (const float*)d_in[12];
    const float* bk2 = (const float*)d_in[13];
    const float* wv2 = (const float*)d_in[14];
    const float* bv2 = (const float*)d_in[15];
    const float* wc2 = (const float*)d_in[16];
    const float* bc2 = (const float*)d_in[17];
    const float* g1  = (const float*)d_in[18];
    const float* g2  = (const float*)d_in[19];

    float* ws  = (float*)d_ws;
    float* out = (float*)d_out;

    proj_kernel<<<dim3(NN / 64, 6, BB), 256, 0, stream>>>(
        x1, x2, wq1, bq1, wk1, bk1, wv1, bv1,
        wq2, bq2, wk2, bk2, wv2, bv2, ws);

    const float* q1 = ws + WS_Q1; const float* k1 = ws + WS_K1;
    const float* q2 = ws + WS_Q2; const float* k2 = ws + WS_K2;
    const unsigned short* v1 = (const unsigned short*)(ws + WS_V1);
    const unsigned short* v2 = (const unsigned short*)(ws + WS_V2);
    float* pp = ws + WS_P;

    attn_mfma<<<dim3(NN / M_BLK, NSEG, BB * 2), 256, 0, stream>>>(
        q1, k1, q2, k2, v1, v2, pp);

    conv_kernel<<<dim3(NN / 256, CC / 8, BB * 2), 256, 0, stream>>>(
        x1, x2, wc1, bc1, wc2, bc2, g1, g2, pp, out);
}